// Round 3
// baseline (467.366 us; speedup 1.0000x reference)
//
#include <hip/hip_runtime.h>
#include <math.h>

#define Bsz 4096
#define Ssz 200
#define Dsz 64
#define NK  5
#define NT  256

__global__ void zero_loss_kernel(float* loss) {
    if (threadIdx.x == 0) *loss = 0.0f;
}

#define FMA4(A, V, S) do { (A).x += (V).x*(S); (A).y += (V).y*(S); \
                           (A).z += (V).z*(S); (A).w += (V).w*(S); } while (0)

__global__ __launch_bounds__(NT, 8) void tan_kernel(
    const int* __restrict__ x, const float* __restrict__ y,
    const float* __restrict__ emb_table,
    const float* __restrict__ att_w, const float* __restrict__ att_b,
    const float* __restrict__ W0, const float* __restrict__ W1,
    const float* __restrict__ W2, const float* __restrict__ W3,
    const float* __restrict__ W4,
    float* __restrict__ out_logit, float* __restrict__ loss_out)
{
    __shared__ alignas(16) int   xs[Ssz];          //  800 B
    __shared__ alignas(16) float att[NK][Ssz];     // 4000 B (logits, then scores)
    __shared__ alignas(16) float urp[4][NK][Dsz];  // 5120 B
    __shared__ alignas(16) float ur[NK][Dsz];      // 1280 B
    __shared__ float wu[18];
    // ~11.3 KB -> 8 blocks/CU (32 waves) if VGPR<=64

    const int b   = blockIdx.x;
    const int tid = threadIdx.x;
    const int w   = tid >> 6;
    const int l   = tid & 63;

    // ---- phase 1: gather rows (2 lanes/row, 8 b128 each) + fused att-logit dot ----
    const float4* awq = (const float4*)att_w;   // [5][16] float4, L1-hot broadcast
    for (int t = tid; t < 2 * Ssz; t += NT) {
        const int s = t >> 1;
        const int h = t & 1;          // == lane&1 on both passes
        const int xi = x[b * Ssz + s];
        if (h == 0) xs[s] = xi;
        const float4* row = (const float4*)(emb_table + (size_t)xi * Dsz) + h * 8;
        float4 v[8];
#pragma unroll
        for (int j = 0; j < 8; ++j) v[j] = row[j];
        float p[NK] = {0.f, 0.f, 0.f, 0.f, 0.f};
#pragma unroll
        for (int j = 0; j < 8; ++j) {
#pragma unroll
            for (int k = 0; k < NK; ++k) {
                float4 a = awq[k * 16 + h * 8 + j];
                p[k] += v[j].x*a.x + v[j].y*a.y + v[j].z*a.z + v[j].w*a.w;
            }
        }
#pragma unroll
        for (int k = 0; k < NK; ++k) p[k] += __shfl_xor(p[k], 1);
        if (h == 0) {
#pragma unroll
            for (int k = 0; k < NK; ++k) att[k][s] = tanhf(p[k] + att_b[k]);
        }
    }
    __syncthreads();

    // ---- softmax over s for each k (4 waves cover 5 k) ----
    for (int k = w; k < NK; k += 4) {
        float vals[4];
        float mx = -1e30f;
#pragma unroll
        for (int j = 0; j < 4; ++j) {
            int s = l + 64 * j;
            vals[j] = (s < Ssz) ? att[k][s] : -1e30f;
            mx = fmaxf(mx, vals[j]);
        }
#pragma unroll
        for (int m = 32; m >= 1; m >>= 1) mx = fmaxf(mx, __shfl_xor(mx, m));
        float sum = 0.f;
#pragma unroll
        for (int j = 0; j < 4; ++j) {
            vals[j] = __expf(vals[j] - mx);
            sum += vals[j];
        }
#pragma unroll
        for (int m = 32; m >= 1; m >>= 1) sum += __shfl_xor(sum, m);
        float inv = 1.0f / sum;
#pragma unroll
        for (int j = 0; j < 4; ++j) {
            int s = l + 64 * j;
            if (s < Ssz) att[k][s] = vals[j] * inv;
        }
    }
    __syncthreads();

    // ---- phase 2: user_rep, re-gather from global (L1/L2/L3-hot) ----
    // thread (c = tid&15, j = tid>>4): float4-frag c, s-quads q = j + 16t
    {
        const int c = tid & 15;
        const int j = tid >> 4;
        float4 acc[NK];
#pragma unroll
        for (int k = 0; k < NK; ++k) acc[k] = float4{0.f, 0.f, 0.f, 0.f};
        for (int q = j; q < 50; q += 16) {
            const int4 xi4 = *(const int4*)(xs + 4 * q);
            float4 v0 = ((const float4*)(emb_table + (size_t)xi4.x * Dsz))[c];
            float4 v1 = ((const float4*)(emb_table + (size_t)xi4.y * Dsz))[c];
            float4 v2 = ((const float4*)(emb_table + (size_t)xi4.z * Dsz))[c];
            float4 v3 = ((const float4*)(emb_table + (size_t)xi4.w * Dsz))[c];
#pragma unroll
            for (int k = 0; k < NK; ++k) {
                float4 sc = ((const float4*)att[k])[q];
                FMA4(acc[k], v0, sc.x);
                FMA4(acc[k], v1, sc.y);
                FMA4(acc[k], v2, sc.z);
                FMA4(acc[k], v3, sc.w);
            }
        }
        // reduce over the 4 j's within this wave (lane bits 4,5)
        float* af = (float*)acc;
#pragma unroll
        for (int i = 0; i < 20; ++i) {
            af[i] += __shfl_xor(af[i], 16);
            af[i] += __shfl_xor(af[i], 32);
        }
        if (l < 16) {
#pragma unroll
            for (int k = 0; k < NK; ++k)
                *(float4*)&urp[w][k][l * 4] = acc[k];
        }
    }
    __syncthreads();

    // combine 4 wave-partials
    for (int i = tid; i < NK * Dsz; i += NT) {
        const int k = i >> 6, d = i & 63;
        ur[k][d] = urp[0][k][d] + urp[1][k][d] + urp[2][k][d] + urp[3][k][d];
    }
    __syncthreads();

    // ---- W_user[j] = ur[g(j)] . W_g[r(j)]  (18 dots of 64) ----
    for (int j = w; j < 18; j += 4) {
        const float* Wp; int g, c0;
        if      (j < 2)  { g = 0; c0 = 0;  Wp = W0; }
        else if (j < 6)  { g = 1; c0 = 2;  Wp = W1; }
        else if (j < 10) { g = 2; c0 = 6;  Wp = W2; }
        else if (j < 12) { g = 3; c0 = 10; Wp = W3; }
        else             { g = 4; c0 = 12; Wp = W4; }
        float p = ur[g][l] * Wp[(j - c0) * Dsz + l];
#pragma unroll
        for (int m = 32; m >= 1; m >>= 1) p += __shfl_xor(p, m);
        if (l == 0) wu[j] = p;
    }
    __syncthreads();

    // ---- per-group softmax -> logits; cross-entropy -> loss (5 lanes of wave 0) ----
    if (w == 0) {
        float lossb = 0.f;
        if (l < NK) {
            const int LEN[5] = {2, 4, 4, 2, 6};
            const int C0[5]  = {0, 2, 6, 10, 12};
            const int g = l, c0 = C0[g], len = LEN[g];
            float* op = out_logit + (size_t)b * 18;
            const float* yp = y + (size_t)b * 18;
            float mx = -1e30f;
            for (int j = 0; j < len; ++j) mx = fmaxf(mx, wu[c0 + j]);
            float sum = 0.f;
            for (int j = 0; j < len; ++j) sum += __expf(wu[c0 + j] - mx);
            float inv = 1.0f / sum;
            float lse = mx + __logf(sum);
            for (int j = 0; j < len; ++j) {
                op[c0 + j] = __expf(wu[c0 + j] - mx) * inv;
                lossb += (lse - wu[c0 + j]) * yp[c0 + j];
            }
        }
#pragma unroll
        for (int m = 1; m <= 4; m <<= 1) lossb += __shfl_xor(lossb, m);
        if (l == 0) atomicAdd(loss_out, lossb * (1.0f / Bsz));
    }
}

extern "C" void kernel_launch(void* const* d_in, const int* in_sizes, int n_in,
                              void* d_out, int out_size, void* d_ws, size_t ws_size,
                              hipStream_t stream) {
    const int*   x   = (const int*)d_in[0];
    const float* y   = (const float*)d_in[1];
    const float* emb = (const float*)d_in[2];
    const float* aw  = (const float*)d_in[3];
    const float* ab  = (const float*)d_in[4];
    const float* W0  = (const float*)d_in[5];
    const float* W1  = (const float*)d_in[6];
    const float* W2  = (const float*)d_in[7];
    const float* W3  = (const float*)d_in[8];
    const float* W4  = (const float*)d_in[9];
    float* out  = (float*)d_out;
    float* loss = out + (size_t)Bsz * 18;

    zero_loss_kernel<<<1, 64, 0, stream>>>(loss);
    tan_kernel<<<Bsz, NT, 0, stream>>>(x, y, emb, aw, ab,
                                       W0, W1, W2, W3, W4, out, loss);
}

// Round 4
// 210.620 us; speedup vs baseline: 2.2190x; 2.2190x over previous
//
#include <hip/hip_runtime.h>
#include <math.h>

#define Bsz 4096
#define Ssz 200
#define Dsz 64
#define NK  5
#define NT  512
#define ROWH 72   // halves per emb row in LDS (144 B) -> bank-conflict-free patterns

typedef _Float16 half_t;
typedef _Float16 h2 __attribute__((ext_vector_type(2)));

__device__ inline h2 shfl_xor_h2(h2 v, int m) {
    int iv = __builtin_bit_cast(int, v);
    iv = __shfl_xor(iv, m);
    return __builtin_bit_cast(h2, iv);
}

__global__ void loss_reduce_kernel(const float* __restrict__ pb,
                                   float* __restrict__ loss) {
    const int l = threadIdx.x;
    float s = 0.f;
    for (int i = l; i < Bsz; i += 64) s += pb[i];
#pragma unroll
    for (int m = 32; m >= 1; m >>= 1) s += __shfl_xor(s, m);
    if (l == 0) *loss = s * (1.0f / Bsz);
}

__global__ __launch_bounds__(NT, 4) void tan_kernel(
    const int* __restrict__ x, const float* __restrict__ y,
    const float* __restrict__ emb_table,
    const float* __restrict__ att_w, const float* __restrict__ att_b,
    const float* __restrict__ W0, const float* __restrict__ W1,
    const float* __restrict__ W2, const float* __restrict__ W3,
    const float* __restrict__ W4,
    float* __restrict__ out_logit, float* __restrict__ loss_ws)
{
    __shared__ alignas(16) half_t embh[Ssz * ROWH];      // 28800 B
    __shared__ alignas(16) float  att[NK][Ssz];          //  4000 B
    __shared__ alignas(16) half_t urph[8][NK][Dsz];      //  5120 B
    __shared__ alignas(16) float  ur[NK][Dsz];           //  1280 B
    __shared__ float wu[18];
    // total ~39.3 KB -> 4 blocks/CU -> 32 waves/CU

    const int b   = blockIdx.x;
    const int tid = threadIdx.x;
    const int w   = tid >> 6;
    const int l   = tid & 63;

    // ---- phase 1: gather (2 lanes/row, chunked 4x b128) + fused att dot (fp32)
    //      + fp16 pack into LDS ----
    if (tid < 2 * Ssz) {
        const int s = tid >> 1;
        const int h = tid & 1;                    // == lane&1
        const int xi = x[b * Ssz + s];
        const float4* row = (const float4*)(emb_table + (size_t)xi * Dsz) + h * 8;
        const float4* awq = (const float4*)att_w; // [5][16] float4, L1-hot
        float p[NK] = {0.f, 0.f, 0.f, 0.f, 0.f};
        half_t* dst = embh + s * ROWH + h * 32;
#pragma unroll
        for (int ch = 0; ch < 2; ++ch) {
            float4 v[4];
#pragma unroll
            for (int j = 0; j < 4; ++j) v[j] = row[ch * 4 + j];
#pragma unroll
            for (int j = 0; j < 4; ++j) {
#pragma unroll
                for (int k = 0; k < NK; ++k) {
                    float4 a = awq[k * 16 + h * 8 + ch * 4 + j];
                    p[k] += v[j].x*a.x + v[j].y*a.y + v[j].z*a.z + v[j].w*a.w;
                }
            }
            union { half_t hh[16]; uint4 q[2]; } u;
#pragma unroll
            for (int i = 0; i < 16; ++i) u.hh[i] = (half_t)(((const float*)v)[i]);
            *(uint4*)(dst + ch * 16)     = u.q[0];
            *(uint4*)(dst + ch * 16 + 8) = u.q[1];
        }
#pragma unroll
        for (int k = 0; k < NK; ++k) p[k] += __shfl_xor(p[k], 1);
        if (h == 0) {
#pragma unroll
            for (int k = 0; k < NK; ++k) att[k][s] = tanhf(p[k] + att_b[k]);
        }
    }
    __syncthreads();

    // ---- softmax over s for each k (waves 0..4) ----
    if (w < NK) {
        const int k = w;
        float vals[4];
        float mx = -1e30f;
#pragma unroll
        for (int j = 0; j < 4; ++j) {
            int s = l + 64 * j;
            vals[j] = (s < Ssz) ? att[k][s] : -1e30f;
            mx = fmaxf(mx, vals[j]);
        }
#pragma unroll
        for (int m = 32; m >= 1; m >>= 1) mx = fmaxf(mx, __shfl_xor(mx, m));
        float sum = 0.f;
#pragma unroll
        for (int j = 0; j < 4; ++j) {
            vals[j] = __expf(vals[j] - mx);
            sum += vals[j];
        }
#pragma unroll
        for (int m = 32; m >= 1; m >>= 1) sum += __shfl_xor(sum, m);
        float inv = 1.0f / sum;
#pragma unroll
        for (int j = 0; j < 4; ++j) {
            int s = l + 64 * j;
            if (s < Ssz) att[k][s] = vals[j] * inv;
        }
    }
    __syncthreads();

    // ---- phase 2: user_rep, packed-fp16 accumulate from LDS ----
    // thread (c = tid&7, j = tid>>3): d-frag [c*8, c*8+8), rows s = j + 64t
    {
        const int c = tid & 7;
        const int j = tid >> 3;
        h2 acc[NK][4];
#pragma unroll
        for (int k = 0; k < NK; ++k)
#pragma unroll
            for (int i = 0; i < 4; ++i) acc[k][i] = (h2){(half_t)0, (half_t)0};
#pragma unroll
        for (int t = 0; t < 4; ++t) {
            const int s = j + 64 * t;
            if (s < Ssz) {
                union { uint4 q; h2 hh[4]; } u;
                u.q = *(const uint4*)(embh + s * ROWH + c * 8);
#pragma unroll
                for (int k = 0; k < NK; ++k) {
                    half_t f = (half_t)att[k][s];
                    h2 sc = (h2){f, f};
#pragma unroll
                    for (int i = 0; i < 4; ++i) acc[k][i] += u.hh[i] * sc;
                }
            }
        }
        // reduce across the 8 j's within this wave (lane bits 3,4,5)
#pragma unroll
        for (int k = 0; k < NK; ++k)
#pragma unroll
            for (int i = 0; i < 4; ++i) {
                acc[k][i] += shfl_xor_h2(acc[k][i], 8);
                acc[k][i] += shfl_xor_h2(acc[k][i], 16);
                acc[k][i] += shfl_xor_h2(acc[k][i], 32);
            }
        if (l < 8) {
#pragma unroll
            for (int k = 0; k < NK; ++k) {
                union { h2 a[4]; uint4 q; } uu;
#pragma unroll
                for (int i = 0; i < 4; ++i) uu.a[i] = acc[k][i];
                *(uint4*)(&urph[w][k][l * 8]) = uu.q;
            }
        }
    }
    __syncthreads();

    // combine the 8 wave-partials -> fp32 ur
    if (tid < NK * Dsz) {
        const int k = tid >> 6, d = tid & 63;
        float ssum = 0.f;
#pragma unroll
        for (int jj = 0; jj < 8; ++jj) ssum += (float)urph[jj][k][d];
        ur[k][d] = ssum;
    }
    __syncthreads();

    // ---- W_user[j] = ur[g(j)] . W_g[r(j)]  (18 dots of 64) ----
    for (int j = w; j < 18; j += 8) {
        const float* Wp; int g, c0;
        if      (j < 2)  { g = 0; c0 = 0;  Wp = W0; }
        else if (j < 6)  { g = 1; c0 = 2;  Wp = W1; }
        else if (j < 10) { g = 2; c0 = 6;  Wp = W2; }
        else if (j < 12) { g = 3; c0 = 10; Wp = W3; }
        else             { g = 4; c0 = 12; Wp = W4; }
        float p = ur[g][l] * Wp[(j - c0) * Dsz + l];
#pragma unroll
        for (int m = 32; m >= 1; m >>= 1) p += __shfl_xor(p, m);
        if (l == 0) wu[j] = p;
    }
    __syncthreads();

    // ---- per-group softmax -> logits; cross-entropy -> per-block partial ----
    if (w == 0) {
        float lossb = 0.f;
        if (l < NK) {
            const int LEN[5] = {2, 4, 4, 2, 6};
            const int C0[5]  = {0, 2, 6, 10, 12};
            const int g = l, c0 = C0[g], len = LEN[g];
            float* op = out_logit + (size_t)b * 18;
            const float* yp = y + (size_t)b * 18;
            float mx = -1e30f;
            for (int j = 0; j < len; ++j) mx = fmaxf(mx, wu[c0 + j]);
            float sum = 0.f;
            for (int j = 0; j < len; ++j) sum += __expf(wu[c0 + j] - mx);
            float inv = 1.0f / sum;
            float lse = mx + __logf(sum);
            for (int j = 0; j < len; ++j) {
                op[c0 + j] = __expf(wu[c0 + j] - mx) * inv;
                lossb += (lse - wu[c0 + j]) * yp[c0 + j];
            }
        }
#pragma unroll
        for (int m = 1; m <= 4; m <<= 1) lossb += __shfl_xor(lossb, m);
        if (l == 0) loss_ws[b] = lossb;
    }
}

extern "C" void kernel_launch(void* const* d_in, const int* in_sizes, int n_in,
                              void* d_out, int out_size, void* d_ws, size_t ws_size,
                              hipStream_t stream) {
    const int*   x   = (const int*)d_in[0];
    const float* y   = (const float*)d_in[1];
    const float* emb = (const float*)d_in[2];
    const float* aw  = (const float*)d_in[3];
    const float* ab  = (const float*)d_in[4];
    const float* W0  = (const float*)d_in[5];
    const float* W1  = (const float*)d_in[6];
    const float* W2  = (const float*)d_in[7];
    const float* W3  = (const float*)d_in[8];
    const float* W4  = (const float*)d_in[9];
    float* out  = (float*)d_out;
    float* loss = out + (size_t)Bsz * 18;
    float* pb   = (float*)d_ws;   // 4096 per-block loss partials

    tan_kernel<<<Bsz, NT, 0, stream>>>(x, y, emb, aw, ab,
                                       W0, W1, W2, W3, W4, out, pb);
    loss_reduce_kernel<<<1, 64, 0, stream>>>(pb, loss);
}

// Round 5
// 164.040 us; speedup vs baseline: 2.8491x; 1.2840x over previous
//
#include <hip/hip_runtime.h>
#include <math.h>

#define Bsz 4096
#define Ssz 200
#define Dsz 64
#define NK  5
#define NT  512
#define ROWH 72   // halves per emb row in LDS (144 B): bank-uniform for all patterns

typedef _Float16 half_t;
typedef _Float16 h2 __attribute__((ext_vector_type(2)));

__device__ inline h2 shfl_xor_h2(h2 v, int m) {
    int iv = __builtin_bit_cast(int, v);
    iv = __shfl_xor(iv, m);
    return __builtin_bit_cast(h2, iv);
}

__device__ inline float fdot2(h2 a, h2 b, float c) {
#if __has_builtin(__builtin_amdgcn_fdot2)
    return __builtin_amdgcn_fdot2(a, b, c, false);
#else
    return c + (float)a.x * (float)b.x + (float)a.y * (float)b.y;
#endif
}

__global__ void loss_reduce_kernel(const float* __restrict__ pb,
                                   float* __restrict__ loss) {
    const int l = threadIdx.x;
    float s = 0.f;
    for (int i = l; i < Bsz; i += 64) s += pb[i];
#pragma unroll
    for (int m = 32; m >= 1; m >>= 1) s += __shfl_xor(s, m);
    if (l == 0) *loss = s * (1.0f / Bsz);
}

__global__ __launch_bounds__(NT, 8) void tan_kernel(
    const int* __restrict__ x, const float* __restrict__ y,
    const float* __restrict__ emb_table,
    const float* __restrict__ att_w, const float* __restrict__ att_b,
    const float* __restrict__ W0, const float* __restrict__ W1,
    const float* __restrict__ W2, const float* __restrict__ W3,
    const float* __restrict__ W4,
    float* __restrict__ out_logit, float* __restrict__ loss_ws)
{
    __shared__ alignas(16) half_t embh[Ssz * ROWH];      // 28800 B
    __shared__ alignas(16) float  att[NK][Ssz];          //  4000 B
    __shared__ alignas(16) h2     awh[NK * 32];          //  1280 B (att_w as h2)
    __shared__ alignas(16) half_t urph[8][NK][Dsz];      //  5120 B
    __shared__ alignas(16) float  ur[NK][Dsz];           //  1280 B
    __shared__ alignas(16) int    xs[Ssz];               //   800 B
    __shared__ float wu[18];
    // total ~40.3 KB -> 4 blocks/CU -> 32 waves/CU

    const int b   = blockIdx.x;
    const int tid = threadIdx.x;
    const int w   = tid >> 6;
    const int l   = tid & 63;

    // ---- P0: stage x indices (threads 0..199) + att_w->h2 (threads 256..415) ----
    if (tid < Ssz) xs[tid] = x[b * Ssz + tid];
    if (tid >= 256 && tid < 256 + NK * 32) {
        const int t = tid - 256;
        awh[t] = (h2){(half_t)att_w[2 * t], (half_t)att_w[2 * t + 1]};
    }
    __syncthreads();

    // ---- P1: coalesced gather, 16 lanes/row, 7 chunk-loads in flight/thread ----
    {
        float4 v[7];
#pragma unroll
        for (int p = 0; p < 7; ++p) {
            int i = tid + NT * p;
            if (i > Ssz * 16 - 1) i = Ssz * 16 - 1;
            const int s = i >> 4, c = i & 15;
            v[p] = ((const float4*)(emb_table + (size_t)xs[s] * Dsz))[c];
        }
#pragma unroll
        for (int p = 0; p < 7; ++p) {
            const int i = tid + NT * p;
            if (p < 6 || i < Ssz * 16) {
                const int s = i >> 4, c = i & 15;
                h2 a  = (h2){(half_t)v[p].x, (half_t)v[p].y};
                h2 b2 = (h2){(half_t)v[p].z, (half_t)v[p].w};
                uint2 u = { __builtin_bit_cast(unsigned, a),
                            __builtin_bit_cast(unsigned, b2) };
                *(uint2*)(embh + s * ROWH + c * 4) = u;
            }
        }
    }
    __syncthreads();

    // ---- P1.5: attention logits via fdot2, 2 threads/row ----
    if (tid < 2 * Ssz) {
        const int s = tid >> 1, h = tid & 1;
        union { uint4 q[4]; h2 hh[16]; } ue;
        const uint4* rp = (const uint4*)(embh + s * ROWH + h * 32);
#pragma unroll
        for (int i = 0; i < 4; ++i) ue.q[i] = rp[i];
        float acc[NK];
#pragma unroll 1
        for (int k = 0; k < NK; ++k) {
            union { uint4 q[4]; h2 hh[16]; } ua;
            const uint4* ap = (const uint4*)(awh + k * 32 + h * 16);
#pragma unroll
            for (int i = 0; i < 4; ++i) ua.q[i] = ap[i];
            float a = 0.f;
#pragma unroll
            for (int i = 0; i < 16; ++i) a = fdot2(ue.hh[i], ua.hh[i], a);
            acc[k] = a;
        }
#pragma unroll
        for (int k = 0; k < NK; ++k) acc[k] += __shfl_xor(acc[k], 1);
        if (h == 0) {
#pragma unroll
            for (int k = 0; k < NK; ++k) att[k][s] = tanhf(acc[k] + att_b[k]);
        }
    }
    __syncthreads();

    // ---- P2: softmax over s for each k (waves 0..4) ----
    if (w < NK) {
        const int k = w;
        float vals[4];
        float mx = -1e30f;
#pragma unroll
        for (int j = 0; j < 4; ++j) {
            int s = l + 64 * j;
            vals[j] = (s < Ssz) ? att[k][s] : -1e30f;
            mx = fmaxf(mx, vals[j]);
        }
#pragma unroll
        for (int m = 32; m >= 1; m >>= 1) mx = fmaxf(mx, __shfl_xor(mx, m));
        float sum = 0.f;
#pragma unroll
        for (int j = 0; j < 4; ++j) {
            vals[j] = __expf(vals[j] - mx);
            sum += vals[j];
        }
#pragma unroll
        for (int m = 32; m >= 1; m >>= 1) sum += __shfl_xor(sum, m);
        float inv = 1.0f / sum;
#pragma unroll
        for (int j = 0; j < 4; ++j) {
            int s = l + 64 * j;
            if (s < Ssz) att[k][s] = vals[j] * inv;
        }
    }
    __syncthreads();

    // ---- P3: user_rep, packed-fp16 accumulate from LDS ----
    {
        const int c = tid & 7;
        const int j = tid >> 3;
        h2 acc[NK][4];
#pragma unroll
        for (int k = 0; k < NK; ++k)
#pragma unroll
            for (int i = 0; i < 4; ++i) acc[k][i] = (h2){(half_t)0, (half_t)0};
#pragma unroll
        for (int t = 0; t < 4; ++t) {
            const int s = j + 64 * t;
            if (s < Ssz) {
                union { uint4 q; h2 hh[4]; } u;
                u.q = *(const uint4*)(embh + s * ROWH + c * 8);
#pragma unroll
                for (int k = 0; k < NK; ++k) {
                    half_t f = (half_t)att[k][s];
                    h2 sc = (h2){f, f};
#pragma unroll
                    for (int i = 0; i < 4; ++i) acc[k][i] += u.hh[i] * sc;
                }
            }
        }
#pragma unroll
        for (int k = 0; k < NK; ++k)
#pragma unroll
            for (int i = 0; i < 4; ++i) {
                acc[k][i] += shfl_xor_h2(acc[k][i], 8);
                acc[k][i] += shfl_xor_h2(acc[k][i], 16);
                acc[k][i] += shfl_xor_h2(acc[k][i], 32);
            }
        if (l < 8) {
#pragma unroll
            for (int k = 0; k < NK; ++k) {
                union { h2 a[4]; uint4 q; } uu;
#pragma unroll
                for (int i = 0; i < 4; ++i) uu.a[i] = acc[k][i];
                *(uint4*)(&urph[w][k][l * 8]) = uu.q;
            }
        }
    }
    __syncthreads();

    // ---- P4: combine the 8 wave-partials -> fp32 ur ----
    if (tid < NK * Dsz) {
        const int k = tid >> 6, d = tid & 63;
        float ssum = 0.f;
#pragma unroll
        for (int jj = 0; jj < 8; ++jj) ssum += (float)urph[jj][k][d];
        ur[k][d] = ssum;
    }
    __syncthreads();

    // ---- P5: W_user[j] = ur[g(j)] . W_g[r(j)]  (18 dots of 64) ----
    for (int j = w; j < 18; j += 8) {
        const float* Wp; int g, c0;
        if      (j < 2)  { g = 0; c0 = 0;  Wp = W0; }
        else if (j < 6)  { g = 1; c0 = 2;  Wp = W1; }
        else if (j < 10) { g = 2; c0 = 6;  Wp = W2; }
        else if (j < 12) { g = 3; c0 = 10; Wp = W3; }
        else             { g = 4; c0 = 12; Wp = W4; }
        float p = ur[g][l] * Wp[(j - c0) * Dsz + l];
#pragma unroll
        for (int m = 32; m >= 1; m >>= 1) p += __shfl_xor(p, m);
        if (l == 0) wu[j] = p;
    }
    __syncthreads();

    // ---- P6: per-group softmax -> logits; CE -> per-block partial ----
    if (w == 0) {
        float lossb = 0.f;
        if (l < NK) {
            const int LEN[5] = {2, 4, 4, 2, 6};
            const int C0[5]  = {0, 2, 6, 10, 12};
            const int g = l, c0 = C0[g], len = LEN[g];
            float* op = out_logit + (size_t)b * 18;
            const float* yp = y + (size_t)b * 18;
            float mx = -1e30f;
            for (int j = 0; j < len; ++j) mx = fmaxf(mx, wu[c0 + j]);
            float sum = 0.f;
            for (int j = 0; j < len; ++j) sum += __expf(wu[c0 + j] - mx);
            float inv = 1.0f / sum;
            float lse = mx + __logf(sum);
            for (int j = 0; j < len; ++j) {
                op[c0 + j] = __expf(wu[c0 + j] - mx) * inv;
                lossb += (lse - wu[c0 + j]) * yp[c0 + j];
            }
        }
#pragma unroll
        for (int m = 1; m <= 4; m <<= 1) lossb += __shfl_xor(lossb, m);
        if (l == 0) loss_ws[b] = lossb;
    }
}

extern "C" void kernel_launch(void* const* d_in, const int* in_sizes, int n_in,
                              void* d_out, int out_size, void* d_ws, size_t ws_size,
                              hipStream_t stream) {
    const int*   x   = (const int*)d_in[0];
    const float* y   = (const float*)d_in[1];
    const float* emb = (const float*)d_in[2];
    const float* aw  = (const float*)d_in[3];
    const float* ab  = (const float*)d_in[4];
    const float* W0  = (const float*)d_in[5];
    const float* W1  = (const float*)d_in[6];
    const float* W2  = (const float*)d_in[7];
    const float* W3  = (const float*)d_in[8];
    const float* W4  = (const float*)d_in[9];
    float* out  = (float*)d_out;
    float* loss = out + (size_t)Bsz * 18;
    float* pb   = (float*)d_ws;   // 4096 per-block loss partials

    tan_kernel<<<Bsz, NT, 0, stream>>>(x, y, emb, aw, ab,
                                       W0, W1, W2, W3, W4, out, pb);
    loss_reduce_kernel<<<1, 64, 0, stream>>>(pb, loss);
}

// Round 6
// 156.836 us; speedup vs baseline: 2.9800x; 1.0459x over previous
//
#include <hip/hip_runtime.h>
#include <math.h>

#define Bsz 4096
#define Ssz 200
#define Dsz 64
#define NK  5
#define NT  512
#define ROWH 72   // halves per emb row in LDS (144 B): b128-aligned every row, bank-balanced
#define AWS  72   // aw_h row stride (halves)

typedef _Float16 half_t;
typedef _Float16 h2 __attribute__((ext_vector_type(2)));
typedef _Float16 h8 __attribute__((ext_vector_type(8)));
typedef float    f4v __attribute__((ext_vector_type(4)));

__device__ inline h2 shfl_xor_h2(h2 v, int m) {
    int iv = __builtin_bit_cast(int, v);
    iv = __shfl_xor(iv, m);
    return __builtin_bit_cast(h2, iv);
}

__global__ void zero_loss_kernel(float* loss) {
    if (threadIdx.x == 0) *loss = 0.0f;
}

__global__ __launch_bounds__(NT, 8) void tan_kernel(
    const int* __restrict__ x, const float* __restrict__ y,
    const float* __restrict__ emb_table,
    const float* __restrict__ att_w, const float* __restrict__ att_b,
    const float* __restrict__ W0, const float* __restrict__ W1,
    const float* __restrict__ W2, const float* __restrict__ W3,
    const float* __restrict__ W4,
    float* __restrict__ out_logit, float* __restrict__ loss_out)
{
    __shared__ alignas(16) half_t embh[208 * ROWH];      // 29952 B (rows 200-207 zeroed)
    __shared__ alignas(16) half_t att_h[NK][208];        //  2080 B (logits, then scores)
    __shared__ alignas(16) half_t aw_h[16 * AWS];        //  2304 B (rows 5-15 zeroed)
    __shared__ alignas(16) half_t urph[8][NK][Dsz];      //  5120 B
    __shared__ alignas(16) int    xs[Ssz];               //   800 B
    __shared__ float wu[18];                             //    72 B
    // total ~40.3 KB -> 4 blocks/CU -> 32 waves/CU (HW wave cap)

    const int b   = blockIdx.x;
    const int tid = threadIdx.x;
    const int w   = tid >> 6;
    const int l   = tid & 63;

    // ---- P0: stage x; aw -> fp16 (pad to 16 rows); zero emb pad rows ----
    if (tid < Ssz) xs[tid] = x[b * Ssz + tid];
    for (int i = tid; i < 1024; i += NT)
        aw_h[(i >> 6) * AWS + (i & 63)] =
            ((i >> 6) < NK) ? (half_t)att_w[i] : (half_t)0;
    {
        uint4 zz = {0, 0, 0, 0};
        uint4* zp = (uint4*)(embh + 200 * ROWH);
        for (int i = tid; i < 72; i += NT) zp[i] = zz;
    }
    __syncthreads();

    // ---- P1: coalesced gather, 16 lanes/row, 7 chunk-loads in flight/thread ----
    {
        float4 v[7];
#pragma unroll
        for (int p = 0; p < 7; ++p) {
            int i = tid + NT * p;
            if (i > Ssz * 16 - 1) i = Ssz * 16 - 1;
            const int s = i >> 4, c = i & 15;
            v[p] = ((const float4*)(emb_table + (size_t)xs[s] * Dsz))[c];
        }
#pragma unroll
        for (int p = 0; p < 7; ++p) {
            const int i = tid + NT * p;
            if (p < 6 || i < Ssz * 16) {
                const int s = i >> 4, c = i & 15;
                h2 a  = (h2){(half_t)v[p].x, (half_t)v[p].y};
                h2 b2 = (h2){(half_t)v[p].z, (half_t)v[p].w};
                uint2 u = { __builtin_bit_cast(unsigned, a),
                            __builtin_bit_cast(unsigned, b2) };
                *(uint2*)(embh + s * ROWH + c * 4) = u;
            }
        }
    }
    __syncthreads();

    // ---- P1.5: attention logits via MFMA: C[k][s] = aw(16x64) x emb^T(64x16/tile) ----
    {
        const int lm = l & 15;   // A: m (attr row) / B,C: n (s within tile)
        const int lq = l >> 4;   // quad -> k-dim chunk / C row group
        h8 a0 = *(const h8*)(aw_h + lm * AWS + lq * 8);
        h8 a1 = *(const h8*)(aw_h + lm * AWS + lq * 8 + 32);
        for (int t = w; t < 13; t += 8) {
            const int s = t * 16 + lm;
            h8 b0 = *(const h8*)(embh + s * ROWH + lq * 8);
            h8 b1 = *(const h8*)(embh + s * ROWH + lq * 8 + 32);
            f4v acc = {0.f, 0.f, 0.f, 0.f};
            acc = __builtin_amdgcn_mfma_f32_16x16x32_f16(a0, b0, acc, 0, 0, 0);
            acc = __builtin_amdgcn_mfma_f32_16x16x32_f16(a1, b1, acc, 0, 0, 0);
#pragma unroll
            for (int r = 0; r < 4; ++r) {
                const int k = lq * 4 + r;
                if (k < NK)
                    att_h[k][s] = (half_t)tanhf(acc[r] + att_b[k]);
            }
        }
    }
    __syncthreads();

    // ---- P2: softmax over s per k (waves 0..4); scores written back as fp16 ----
    if (w < NK) {
        const int k = w;
        float vals[4];
        float mx = -1e30f;
#pragma unroll
        for (int j = 0; j < 4; ++j) {
            int s = l + 64 * j;
            vals[j] = (s < Ssz) ? (float)att_h[k][s] : -1e30f;
            mx = fmaxf(mx, vals[j]);
        }
#pragma unroll
        for (int m = 32; m >= 1; m >>= 1) mx = fmaxf(mx, __shfl_xor(mx, m));
        float sum = 0.f;
#pragma unroll
        for (int j = 0; j < 4; ++j) {
            vals[j] = __expf(vals[j] - mx);
            sum += vals[j];
        }
#pragma unroll
        for (int m = 32; m >= 1; m >>= 1) sum += __shfl_xor(sum, m);
        float inv = 1.0f / sum;
#pragma unroll
        for (int j = 0; j < 4; ++j) {
            int s = l + 64 * j;
            if (s < Ssz) att_h[k][s] = (half_t)(vals[j] * inv);
        }
    }
    __syncthreads();

    // ---- P3: user_rep, packed-fp16; thread (c=tid&15, j=tid>>4), s = j + 32t ----
    {
        const int c = tid & 15;          // d-frag [c*4, c*4+4)
        const int j = tid >> 4;          // 32 s-groups
        h2 acc[NK][2];
#pragma unroll
        for (int k = 0; k < NK; ++k)
#pragma unroll
            for (int i = 0; i < 2; ++i) acc[k][i] = (h2){(half_t)0, (half_t)0};
#pragma unroll
        for (int t = 0; t < 7; ++t) {
            const int s = j + 32 * t;
            if (s < Ssz) {
                union { uint2 q; h2 hh[2]; } u;
                u.q = *(const uint2*)(embh + s * ROWH + c * 4);
#pragma unroll
                for (int k = 0; k < NK; ++k) {
                    half_t f = att_h[k][s];      // 16-lane broadcast
                    h2 sc = (h2){f, f};
                    acc[k][0] += u.hh[0] * sc;
                    acc[k][1] += u.hh[1] * sc;
                }
            }
        }
        // reduce the wave's 4 j-groups (lane bits 4,5)
#pragma unroll
        for (int k = 0; k < NK; ++k)
#pragma unroll
            for (int i = 0; i < 2; ++i) {
                acc[k][i] += shfl_xor_h2(acc[k][i], 16);
                acc[k][i] += shfl_xor_h2(acc[k][i], 32);
            }
        if (l < 16) {
#pragma unroll
            for (int k = 0; k < NK; ++k) {
                union { h2 a[2]; uint2 q; } uu;
                uu.a[0] = acc[k][0]; uu.a[1] = acc[k][1];
                *(uint2*)(&urph[w][k][l * 4]) = uu.q;
            }
        }
    }
    __syncthreads();

    // ---- P5: W_user[j] = ur[g(j)] . W_g[r(j)] (8-partial sum folded in) ----
    for (int j = w; j < 18; j += 8) {
        const float* Wp; int g, c0;
        if      (j < 2)  { g = 0; c0 = 0;  Wp = W0; }
        else if (j < 6)  { g = 1; c0 = 2;  Wp = W1; }
        else if (j < 10) { g = 2; c0 = 6;  Wp = W2; }
        else if (j < 12) { g = 3; c0 = 10; Wp = W3; }
        else             { g = 4; c0 = 12; Wp = W4; }
        float urv = 0.f;
#pragma unroll
        for (int jj = 0; jj < 8; ++jj) urv += (float)urph[jj][g][l];
        float p = urv * Wp[(j - c0) * Dsz + l];
#pragma unroll
        for (int m = 32; m >= 1; m >>= 1) p += __shfl_xor(p, m);
        if (l == 0) wu[j] = p;
    }
    __syncthreads();

    // ---- P6: per-group softmax -> logits; CE -> atomic loss ----
    if (w == 0) {
        float lossb = 0.f;
        if (l < NK) {
            const int LEN[5] = {2, 4, 4, 2, 6};
            const int C0[5]  = {0, 2, 6, 10, 12};
            const int g = l, c0 = C0[g], len = LEN[g];
            float* op = out_logit + (size_t)b * 18;
            const float* yp = y + (size_t)b * 18;
            float mx = -1e30f;
            for (int j = 0; j < len; ++j) mx = fmaxf(mx, wu[c0 + j]);
            float sum = 0.f;
            for (int j = 0; j < len; ++j) sum += __expf(wu[c0 + j] - mx);
            float inv = 1.0f / sum;
            float lse = mx + __logf(sum);
            for (int j = 0; j < len; ++j) {
                op[c0 + j] = __expf(wu[c0 + j] - mx) * inv;
                lossb += (lse - wu[c0 + j]) * yp[c0 + j];
            }
        }
#pragma unroll
        for (int m = 1; m <= 4; m <<= 1) lossb += __shfl_xor(lossb, m);
        if (l == 0) atomicAdd(loss_out, lossb * (1.0f / Bsz));
    }
}

extern "C" void kernel_launch(void* const* d_in, const int* in_sizes, int n_in,
                              void* d_out, int out_size, void* d_ws, size_t ws_size,
                              hipStream_t stream) {
    const int*   x   = (const int*)d_in[0];
    const float* y   = (const float*)d_in[1];
    const float* emb = (const float*)d_in[2];
    const float* aw  = (const float*)d_in[3];
    const float* ab  = (const float*)d_in[4];
    const float* W0  = (const float*)d_in[5];
    const float* W1  = (const float*)d_in[6];
    const float* W2  = (const float*)d_in[7];
    const float* W3  = (const float*)d_in[8];
    const float* W4  = (const float*)d_in[9];
    float* out  = (float*)d_out;
    float* loss = out + (size_t)Bsz * 18;

    zero_loss_kernel<<<1, 64, 0, stream>>>(loss);
    tan_kernel<<<Bsz, NT, 0, stream>>>(x, y, emb, aw, ab,
                                       W0, W1, W2, W3, W4, out, loss);
}